// Round 6
// baseline (662.029 us; speedup 1.0000x reference)
//
#include <hip/hip_runtime.h>
#include <hip/hip_bf16.h>
#include <cstdint>
#include <cstddef>

// Problem constants
#define NT   250000      // total nodes
#define NUU  200000      // users
#define NPP  50000       // products
#define EG   500000      // directed edges
#define E2   1000000     // doubled (undirected)
#define HD   128
#define NBLK_SCAN 977    // ceil(NT/256)
#define RMASK 0x3FFFF    // low 18 bits: src id; bits 18+: tile-local dst row (64-row tiles)

// Workspace layout (bytes) — total 185,451,728 (< proven-available 186,208,008)
#define X_OFF     0ull            // X  [NT*HD] bf16 = 64,000,000
#define R1_OFF    64000000ull     // R1 [NT*HD] bf16 = 64,000,000
#define R2_OFF    128000000ull    // R2 [NUU*HD] bf16 = 51,200,000
#define CNT_OFF   179200000ull    // cnt [NT] i32 (reused as fill) = 1,000,000
#define SPART_OFF 180200000ull    // stats partials 2 layers x 32 x 256 f32 = 65,536
#define SS_OFF    180265536ull    // ss1|ss2: 2 x 256 f32 = 2,048
#define RPTR_OFF  180267584ull    // row_ptr [NT+1] i32 = 1,000,004
#define BSUM_OFF  181267588ull    // block sums [977] i32 = 3,908
#define BMAT_OFF  181271504ull    // bf16 weights: L1[128][256] L2[128][256] PU[128][128] PP[128][64]
#define COL_OFF   181451728ull    // col [E2] i32 = 4,000,000
#define WS_NEED   185451728ull

typedef __hip_bfloat16 bf16;
typedef __attribute__((ext_vector_type(8))) short short8v;
typedef __attribute__((ext_vector_type(4))) float f32x4;

__device__ inline float bflo(unsigned u) { return __builtin_bit_cast(float, u << 16); }
__device__ inline float bfhi(unsigned u) { return __builtin_bit_cast(float, u & 0xffff0000u); }
__device__ inline float b2f(short s) { return __builtin_bit_cast(float, ((unsigned)(unsigned short)s) << 16); }
__device__ inline unsigned short f2bf(float f) { return __builtin_bit_cast(unsigned short, __float2bfloat16(f)); }

__global__ __launch_bounds__(256) void k_zero(int* __restrict__ p, int n) {
    for (int i = blockIdx.x * 256 + threadIdx.x; i < n; i += gridDim.x * 256) p[i] = 0;
}

// ---------------- CSR build ----------------
__global__ __launch_bounds__(256) void k_count(const int* __restrict__ ei, int* __restrict__ cnt) {
    for (int e = blockIdx.x * 256 + threadIdx.x; e < E2; e += gridDim.x * 256) {
        int d = (e < EG) ? ei[e + EG] : ei[e - EG];
        atomicAdd(&cnt[d], 1);
    }
}

__global__ __launch_bounds__(256) void k_scan1(const int* __restrict__ cnt, int* __restrict__ bsum) {
    __shared__ int lds[256];
    int i = blockIdx.x * 256 + threadIdx.x;
    int v = (i < NT) ? cnt[i] : 0;
    lds[threadIdx.x] = v; __syncthreads();
    for (int s = 128; s > 0; s >>= 1) {
        if (threadIdx.x < s) lds[threadIdx.x] += lds[threadIdx.x + s];
        __syncthreads();
    }
    if (threadIdx.x == 0) bsum[blockIdx.x] = lds[0];
}

__global__ __launch_bounds__(1024) void k_scan2(int* __restrict__ bsum) {
    __shared__ int lds[1024];
    int i = threadIdx.x;
    int v = (i < NBLK_SCAN) ? bsum[i] : 0;
    lds[i] = v; __syncthreads();
    for (int off = 1; off < 1024; off <<= 1) {
        int t = (i >= off) ? lds[i - off] : 0;
        __syncthreads();
        lds[i] += t;
        __syncthreads();
    }
    if (i < NBLK_SCAN) bsum[i] = lds[i] - v;   // exclusive
}

__global__ __launch_bounds__(256) void k_scan3(const int* __restrict__ cnt, const int* __restrict__ bsum,
                                               int* __restrict__ rp) {
    __shared__ int lds[256];
    int i = blockIdx.x * 256 + threadIdx.x;
    int v = (i < NT) ? cnt[i] : 0;
    lds[threadIdx.x] = v; __syncthreads();
    for (int off = 1; off < 256; off <<= 1) {
        int t = (threadIdx.x >= off) ? lds[threadIdx.x - off] : 0;
        __syncthreads();
        lds[threadIdx.x] += t;
        __syncthreads();
    }
    if (i < NT) rp[i] = bsum[blockIdx.x] + lds[threadIdx.x] - v;
    if (i == 0 && blockIdx.x == 0) rp[NT] = E2;
}

// col[slot] packs src (18 bits) | tile-local dst row (bits 18+), tiles 64-aligned
__global__ __launch_bounds__(256) void k_fill(const int* __restrict__ ei, const int* __restrict__ rp,
                                              int* __restrict__ fill, int* __restrict__ col) {
    for (int e = blockIdx.x * 256 + threadIdx.x; e < E2; e += gridDim.x * 256) {
        int s = ei[e];
        int d = (e < EG) ? ei[e + EG] : ei[e - EG];
        int slot = rp[d] + atomicAdd(&fill[d], 1);
        col[slot] = s | ((d & 63) << 18);
    }
}

// ---------------- Weight conversion: fp32 -> bf16, stacked/padded ----------------
__global__ __launch_bounds__(256) void k_wcvt(const float* __restrict__ W1l, const float* __restrict__ W1r,
                                              const float* __restrict__ W2l, const float* __restrict__ W2r,
                                              const float* __restrict__ Wu, const float* __restrict__ Wp,
                                              bf16* __restrict__ B) {
    int i = blockIdx.x * 256 + threadIdx.x;
    if (i < 65536) {
        int layer = i >> 15, rem = i & 32767, o = rem >> 8, k = rem & 255;
        const float* W = layer ? ((k < 128) ? W2l : W2r) : ((k < 128) ? W1l : W1r);
        B[i] = __float2bfloat16(W[o * 128 + (k & 127)]);
    } else if (i < 81920) {
        int rem = i - 65536, o = rem >> 7, k = rem & 127;
        B[i] = __float2bfloat16((k < 100) ? Wu[o * 100 + k] : 0.f);
    } else if (i < 90112) {
        int rem = i - 81920, o = rem >> 6, k = rem & 63;
        B[i] = __float2bfloat16((k < 50) ? Wp[o * 50 + k] : 0.f);
    }
}

// ---------------- MFMA projection: X = relu(in @ Wp^T + b), K zero-padded ----------------
template<int DIN, int KPAD>
__global__ __launch_bounds__(256) void k_projm(const float* __restrict__ in, const bf16* __restrict__ Bp,
                                               const float* __restrict__ bias, bf16* __restrict__ outp,
                                               int nrows, int rowbase) {
    const int lane = threadIdx.x & 63;
    const int wid = threadIdx.x >> 6;
    const int wr = wid >> 1, wc = wid & 1;
    const int r15 = lane & 15, l4 = lane >> 4;
    const int tb = blockIdx.x * 128;
    constexpr int NKS = KPAD / 32;

    f32x4 acc[4][4] = {};
#pragma unroll
    for (int ks = 0; ks < NKS; ks++) {
        int kk = ks * 32 + l4 * 8;
        short8v a[4], b[4];
#pragma unroll
        for (int m = 0; m < 4; m++) {
            int r = tb + wr * 64 + m * 16 + r15;
            if (r > nrows - 1) r = nrows - 1;
            const float* src = in + (size_t)r * DIN + kk;
            short8v v;
            if (ks * 32 + 32 <= DIN) {
                const float2* s2 = (const float2*)src;
                float2 f0 = s2[0], f1 = s2[1], f2 = s2[2], f3 = s2[3];
                v[0] = (short)f2bf(f0.x); v[1] = (short)f2bf(f0.y);
                v[2] = (short)f2bf(f1.x); v[3] = (short)f2bf(f1.y);
                v[4] = (short)f2bf(f2.x); v[5] = (short)f2bf(f2.y);
                v[6] = (short)f2bf(f3.x); v[7] = (short)f2bf(f3.y);
            } else {
#pragma unroll
                for (int j = 0; j < 8; j++) {
                    float f = (kk + j < DIN) ? src[j] : 0.f;
                    v[j] = (short)f2bf(f);
                }
            }
            a[m] = v;
        }
#pragma unroll
        for (int n = 0; n < 4; n++) {
            int c = wc * 64 + n * 16 + r15;
            b[n] = *(const short8v*)(Bp + (size_t)c * KPAD + kk);
        }
#pragma unroll
        for (int m = 0; m < 4; m++)
#pragma unroll
            for (int n = 0; n < 4; n++)
                acc[m][n] = __builtin_amdgcn_mfma_f32_16x16x32_bf16(a[m], b[n], acc[m][n], 0, 0, 0);
    }
    float bcol[4];
#pragma unroll
    for (int n = 0; n < 4; n++) bcol[n] = bias[wc * 64 + n * 16 + r15];
#pragma unroll
    for (int m = 0; m < 4; m++)
#pragma unroll
        for (int n = 0; n < 4; n++)
#pragma unroll
            for (int g = 0; g < 4; g++) {
                int row = tb + wr * 64 + m * 16 + l4 * 4 + g;
                if (row < nrows) {
                    float v = fmaxf(acc[m][n][g] + bcol[n], 0.f);
                    outp[(size_t)(rowbase + row) * HD + wc * 64 + n * 16 + r15] = __float2bfloat16(v);
                }
            }
}

// ---------------- Fused SAGE layer, 64-row tiles ----------------
// Phase A (edge-parallel): 16 groups sweep contiguous edge chunks; same-row runs
//   accumulate in registers; on row change flush 8 f32 LDS atomics (swizzled).
// Phase B: K=256 MFMA; ks 0..3 from f32 LDS mean tile (1/deg folded into bf16 cvt),
//   ks 4..7 own rows from global (norm on the fly). Wave w owns rows [16w,16w+16).
template<bool NORM>
__global__ __launch_bounds__(256) void k_gemm(const bf16* __restrict__ hin, const float* __restrict__ ssv,
                                              const int* __restrict__ rp, const int* __restrict__ col,
                                              const bf16* __restrict__ Bmat, const float* __restrict__ blv,
                                              bf16* __restrict__ outp, float* __restrict__ spart,
                                              int store_n) {
    // Load-balance remap: user tiles 0..3124, product tiles 3125..3906, 1-in-5 interleave
    int g = blockIdx.x / 5, pos = blockIdx.x % 5;
    int tile = (pos < 4) ? (g * 4 + pos) : (3125 + g);
    if (pos < 4 && tile > 3124) return;

    __shared__ __align__(16) float fac[64 * 128];   // f32 accum tile, 32 KB, 16B-slot swizzle ^(row&3)
    const int tid = threadIdx.x;
    const int lane = tid & 63;
    const int wq = tid >> 6;
    const int gid = tid >> 4;          // 16 groups
    const int l16 = tid & 15;
    const int fo = l16 * 8;            // feature offset of this lane
    const int tb = tile * 64;

    // zero LDS tile
    f32x4 z = {0.f, 0.f, 0.f, 0.f};
#pragma unroll
    for (int i = 0; i < 8; i++) ((f32x4*)fac)[tid + i * 256] = z;

    float sv[8], tv[8];
    if (NORM) {
#pragma unroll
        for (int j = 0; j < 8; j++) { sv[j] = ssv[fo + j]; tv[j] = ssv[HD + fo + j]; }
    }

    int e0 = rp[tb];
    int e1 = rp[min(tb + 64, NT)];
    int chunk = (e1 - e0 + 15) >> 4;
    int es = e0 + gid * chunk;
    int ee = min(es + chunk, e1);

    __syncthreads();   // tile zeroed before atomics

    float racc[8] = {};
    int rcur = -1;
    auto flushf = [&]() {
#pragma unroll
        for (int j = 0; j < 8; j++)
            atomicAdd(&fac[(rcur << 7) + ((fo + j) ^ ((rcur & 3) << 2))], racc[j]);
    };
    auto proc = [&](int vv, short8v uu, bool live) {
        if (!live) return;
        int r = vv >> 18;
        if (r != rcur) {
            if (rcur >= 0) flushf();
            rcur = r;
#pragma unroll
            for (int j = 0; j < 8; j++) racc[j] = 0.f;
        }
#pragma unroll
        for (int j = 0; j < 8; j++) {
            float f = b2f(uu[j]);
            if (NORM) f = fmaxf(fmaf(f, sv[j], tv[j]), 0.f);
            racc[j] += f;
        }
    };

    for (int p = es; p < ee; p += 4) {
        int n1 = min(p + 1, ee - 1), n2 = min(p + 2, ee - 1), n3 = min(p + 3, ee - 1);
        int v0 = col[p], v1 = col[n1], v2 = col[n2], v3 = col[n3];
        short8v u0 = *(const short8v*)(hin + (size_t)(v0 & RMASK) * HD + fo);
        short8v u1 = *(const short8v*)(hin + (size_t)(v1 & RMASK) * HD + fo);
        short8v u2 = *(const short8v*)(hin + (size_t)(v2 & RMASK) * HD + fo);
        short8v u3 = *(const short8v*)(hin + (size_t)(v3 & RMASK) * HD + fo);
        proc(v0, u0, true);
        proc(v1, u1, p + 1 < ee);
        proc(v2, u2, p + 2 < ee);
        proc(v3, u3, p + 3 < ee);
    }
    if (rcur >= 0) flushf();
    __syncthreads();

    // ---- Phase B: MFMA over K=256; wave wq owns rows [wq*16, wq*16+16) ----
    const int r15 = lane & 15, l4 = lane >> 4;
    const int rl = wq * 16 + r15;      // local A-frag row
    const int gr = tb + rl;
    float inv = 1.f / (float)max(rp[min(gr + 1, NT)] - rp[min(gr, NT)], 1);

    f32x4 acc[8] = {};
#pragma unroll
    for (int ks = 0; ks < 8; ks++) {
        short8v a;
        if (ks < 4) {
            int k0 = ks * 32 + l4 * 8;
            f32x4 A0 = *(const f32x4*)&fac[(rl << 7) + (k0 ^ ((rl & 3) << 2))];
            f32x4 A1 = *(const f32x4*)&fac[(rl << 7) + ((k0 + 4) ^ ((rl & 3) << 2))];
#pragma unroll
            for (int j = 0; j < 4; j++) {
                a[j] = (short)f2bf(A0[j] * inv);
                a[4 + j] = (short)f2bf(A1[j] * inv);
            }
        } else {
            int k2 = (ks - 4) * 32 + l4 * 8;
            int r = min(gr, NT - 1);
            short8v v = *(const short8v*)(hin + (size_t)r * HD + k2);
            if (NORM) {
#pragma unroll
                for (int j = 0; j < 8; j++) {
                    float f = b2f(v[j]);
                    f = fmaxf(fmaf(f, ssv[k2 + j], ssv[HD + k2 + j]), 0.f);
                    v[j] = (short)f2bf(f);
                }
            }
            a = v;
        }
#pragma unroll
        for (int n = 0; n < 8; n++) {
            short8v b = *(const short8v*)(Bmat + (size_t)(n * 16 + r15) * 256 + ks * 32 + l4 * 8);
            acc[n] = __builtin_amdgcn_mfma_f32_16x16x32_bf16(a, b, acc[n], 0, 0, 0);
        }
    }

    // ---- Epilogue: bias, store, BN stats ----
    float ls[8], lq[8];
#pragma unroll
    for (int n = 0; n < 8; n++) {
        float bc = blv[n * 16 + r15];
        ls[n] = 0.f; lq[n] = 0.f;
#pragma unroll
        for (int gg = 0; gg < 4; gg++) {
            int row = tb + wq * 16 + l4 * 4 + gg;
            float v = acc[n][gg] + bc;
            if (row < NT) { ls[n] += v; lq[n] += v * v; }
            if (row < store_n)
                outp[(size_t)row * HD + n * 16 + r15] = __float2bfloat16(v);
        }
    }
    int part = (tile & 31) * 256;
#pragma unroll
    for (int n = 0; n < 8; n++) {
        float s = ls[n], q2 = lq[n];
        s  += __shfl_xor(s, 16);  s  += __shfl_xor(s, 32);
        q2 += __shfl_xor(q2, 16); q2 += __shfl_xor(q2, 32);
        if (l4 == 0) {
            int c = n * 16 + r15;
            atomicAdd(&spart[part + c], s);
            atomicAdd(&spart[part + 128 + c], q2);
        }
    }
}

// ---------------- BN finalize: reduce 32 partials -> per-column scale/shift ----------------
__global__ void k_fin(const float* __restrict__ sp, const float* __restrict__ g,
                      const float* __restrict__ be, float* __restrict__ ssout) {
    int j = threadIdx.x;   // 128
    float m = 0.f, q = 0.f;
    for (int i = 0; i < 32; i++) { m += sp[i * 256 + j]; q += sp[i * 256 + 128 + j]; }
    m *= (1.f / (float)NT);
    q = q * (1.f / (float)NT) - m * m;
    float s = g[j] * rsqrtf(q + 1e-5f);
    ssout[j] = s;
    ssout[HD + j] = be[j] - m * s;
}

// ---------------- Final: out = (relu(bn(raw2)) + x)[:NU] @ Wout^T + bout ----------------
__global__ __launch_bounds__(256) void k_out(const bf16* __restrict__ r2, const float* __restrict__ ss,
                                             const bf16* __restrict__ x, const float* __restrict__ wout,
                                             const float* __restrict__ bout, float* __restrict__ outp) {
    int lane = threadIdx.x & 63;
    int wid = (blockIdx.x * blockDim.x + threadIdx.x) >> 6;
    int nwv = (gridDim.x * blockDim.x) >> 6;
    int j0 = lane * 2;
    float s0 = ss[j0],       s1 = ss[j0 + 1];
    float t0 = ss[HD + j0],  t1 = ss[HD + j0 + 1];
    float w0 = wout[j0], w1 = wout[j0 + 1];
    float bo = bout[0];
    for (int r = wid; r < NUU; r += nwv) {
        unsigned ua = *(const unsigned*)(r2 + (size_t)r * HD + j0);
        unsigned ux = *(const unsigned*)(x + (size_t)r * HD + j0);
        float h0 = fmaxf(fmaf(bflo(ua), s0, t0), 0.f) + bflo(ux);
        float h1 = fmaxf(fmaf(bfhi(ua), s1, t1), 0.f) + bfhi(ux);
        float acc = h0 * w0 + h1 * w1;
#pragma unroll
        for (int off = 32; off; off >>= 1) acc += __shfl_down(acc, off);
        if (lane == 0) outp[r] = acc + bo;
    }
}

extern "C" void kernel_launch(void* const* d_in, const int* in_sizes, int n_in,
                              void* d_out, int out_size, void* d_ws, size_t ws_size,
                              hipStream_t stream) {
    const float* x_u = (const float*)d_in[0];
    const float* x_p = (const float*)d_in[1];
    const int*   ei  = (const int*)d_in[2];
    const float* W_u = (const float*)d_in[3];
    const float* b_u = (const float*)d_in[4];
    const float* W_p = (const float*)d_in[5];
    const float* b_p = (const float*)d_in[6];
    const float* W1l = (const float*)d_in[7];
    const float* b1l = (const float*)d_in[8];
    const float* W1r = (const float*)d_in[9];
    const float* g1  = (const float*)d_in[10];
    const float* be1 = (const float*)d_in[11];
    const float* W2l = (const float*)d_in[12];
    const float* b2l = (const float*)d_in[13];
    const float* W2r = (const float*)d_in[14];
    const float* g2  = (const float*)d_in[15];
    const float* be2 = (const float*)d_in[16];
    const float* Wout = (const float*)d_in[17];
    const float* bout = (const float*)d_in[18];

    float* out = (float*)d_out;

    if (ws_size < WS_NEED) {   // diagnostic fallback (should not trigger)
        k_zero<<<512, 256, 0, stream>>>((int*)d_out, out_size);
        return;
    }

    char* ws = (char*)d_ws;
    bf16* X      = (bf16*)(ws + X_OFF);
    bf16* R1     = (bf16*)(ws + R1_OFF);
    bf16* R2     = (bf16*)(ws + R2_OFF);
    int*  cnt    = (int*)(ws + CNT_OFF);
    float* spart = (float*)(ws + SPART_OFF);
    float* ssbuf = (float*)(ws + SS_OFF);
    int*  rp     = (int*)(ws + RPTR_OFF);
    int*  bsum   = (int*)(ws + BSUM_OFF);
    bf16* Bmat   = (bf16*)(ws + BMAT_OFF);
    int*  col    = (int*)(ws + COL_OFF);

    // Zero cnt + spart + ss (contiguous: 266,896 ints)
    k_zero<<<1043, 256, 0, stream>>>(cnt, 266896);
    k_wcvt<<<352, 256, 0, stream>>>(W1l, W1r, W2l, W2r, W_u, W_p, Bmat);

    // CSR build
    k_count<<<1024, 256, 0, stream>>>(ei, cnt);
    k_scan1<<<NBLK_SCAN, 256, 0, stream>>>(cnt, bsum);
    k_scan2<<<1, 1024, 0, stream>>>(bsum);
    k_scan3<<<NBLK_SCAN, 256, 0, stream>>>(cnt, bsum, rp);
    k_zero<<<977, 256, 0, stream>>>(cnt, NT);          // reuse cnt as fill
    k_fill<<<1024, 256, 0, stream>>>(ei, rp, cnt, col);

    // Projections -> X (bf16), MFMA with zero-padded K
    k_projm<100, 128><<<1563, 256, 0, stream>>>(x_u, Bmat + 65536, b_u, X, NUU, 0);
    k_projm<50, 64><<<391, 256, 0, stream>>>(x_p, Bmat + 81920, b_p, X, NPP, NUU);

    // Layer 1: X -> R1 (+stats1)   grid = 782 groups x 5 (3 no-op blocks)
    k_gemm<false><<<3910, 256, 0, stream>>>(X, nullptr, rp, col, Bmat, b1l, R1, spart, NT);
    k_fin<<<1, 128, 0, stream>>>(spart, g1, be1, ssbuf);

    // Layer 2: f(R1) -> R2 (+stats2), BN1+relu folded into gather and A2 loads
    k_gemm<true><<<3910, 256, 0, stream>>>(R1, ssbuf, rp, col, Bmat + 32768, b2l, R2, spart + 8192, NUU);
    k_fin<<<1, 128, 0, stream>>>(spart + 8192, g2, be2, ssbuf + 256);

    // Output
    k_out<<<2048, 256, 0, stream>>>(R2, ssbuf + 256, X, Wout, bout, out);
}

// Round 7
// 507.037 us; speedup vs baseline: 1.3057x; 1.3057x over previous
//
#include <hip/hip_runtime.h>
#include <hip/hip_bf16.h>
#include <cstdint>
#include <cstddef>

// Problem constants
#define NT   250000      // total nodes
#define NUU  200000      // users
#define NPP  50000       // products
#define EG   500000      // directed edges
#define E2   1000000     // doubled (undirected)
#define HD   128
#define NBLK_SCAN 977    // ceil(NT/256)

// ---------- Fallback (fused) workspace layout — total 185,451,728 ----------
#define X_OFF     0ull
#define R1_OFF    64000000ull
#define R2_OFF    128000000ull
#define CNT_OFF   179200000ull
#define SPART_OFF 180200000ull
#define SS_OFF    180265536ull
#define RPTR_OFF  180267584ull
#define BSUM_OFF  181267588ull
#define BMAT_OFF  181271504ull
#define COL_OFF   181451728ull
#define WS_NEED   185451728ull

// ---------- Split workspace layout — total 198,251,728 ----------
#define CNT2_OFF   0ull            // 1,000,000
#define SPART2_OFF 1000000ull      // 65,536
#define SS2_OFF    1065536ull      // 2,048
#define RPTR2_OFF  1067584ull      // 1,000,004
#define BSUM2_OFF  2067588ull      // 3,908 (+pad)
#define BMAT2_OFF  2071504ull      // 180,224 (16B aligned)
#define COL2_OFF   2251728ull      // 4,000,000
#define X2_OFF     6251728ull      // 64,000,000
#define R1B_OFF    70251728ull     // 64,000,000
#define C2_OFF     134251728ull    // 64,000,000 (M1, M2, R2 share this)
#define WS_SPLIT   198251728ull

typedef __hip_bfloat16 bf16;
typedef __attribute__((ext_vector_type(8))) short short8v;
typedef __attribute__((ext_vector_type(4))) float f32x4;

__device__ inline float bflo(unsigned u) { return __builtin_bit_cast(float, u << 16); }
__device__ inline float bfhi(unsigned u) { return __builtin_bit_cast(float, u & 0xffff0000u); }
__device__ inline float b2f(short s) { return __builtin_bit_cast(float, ((unsigned)(unsigned short)s) << 16); }
__device__ inline unsigned short f2bf(float f) { return __builtin_bit_cast(unsigned short, __float2bfloat16(f)); }

__global__ __launch_bounds__(256) void k_zero(int* __restrict__ p, int n) {
    for (int i = blockIdx.x * 256 + threadIdx.x; i < n; i += gridDim.x * 256) p[i] = 0;
}

// ---------------- CSR build ----------------
__global__ __launch_bounds__(256) void k_count(const int* __restrict__ ei, int* __restrict__ cnt) {
    for (int e = blockIdx.x * 256 + threadIdx.x; e < E2; e += gridDim.x * 256) {
        int d = (e < EG) ? ei[e + EG] : ei[e - EG];
        atomicAdd(&cnt[d], 1);
    }
}

__global__ __launch_bounds__(256) void k_scan1(const int* __restrict__ cnt, int* __restrict__ bsum) {
    __shared__ int lds[256];
    int i = blockIdx.x * 256 + threadIdx.x;
    int v = (i < NT) ? cnt[i] : 0;
    lds[threadIdx.x] = v; __syncthreads();
    for (int s = 128; s > 0; s >>= 1) {
        if (threadIdx.x < s) lds[threadIdx.x] += lds[threadIdx.x + s];
        __syncthreads();
    }
    if (threadIdx.x == 0) bsum[blockIdx.x] = lds[0];
}

__global__ __launch_bounds__(1024) void k_scan2(int* __restrict__ bsum) {
    __shared__ int lds[1024];
    int i = threadIdx.x;
    int v = (i < NBLK_SCAN) ? bsum[i] : 0;
    lds[i] = v; __syncthreads();
    for (int off = 1; off < 1024; off <<= 1) {
        int t = (i >= off) ? lds[i - off] : 0;
        __syncthreads();
        lds[i] += t;
        __syncthreads();
    }
    if (i < NBLK_SCAN) bsum[i] = lds[i] - v;   // exclusive
}

__global__ __launch_bounds__(256) void k_scan3(const int* __restrict__ cnt, const int* __restrict__ bsum,
                                               int* __restrict__ rp) {
    __shared__ int lds[256];
    int i = blockIdx.x * 256 + threadIdx.x;
    int v = (i < NT) ? cnt[i] : 0;
    lds[threadIdx.x] = v; __syncthreads();
    for (int off = 1; off < 256; off <<= 1) {
        int t = (threadIdx.x >= off) ? lds[threadIdx.x - off] : 0;
        __syncthreads();
        lds[threadIdx.x] += t;
        __syncthreads();
    }
    if (i < NT) rp[i] = bsum[blockIdx.x] + lds[threadIdx.x] - v;
    if (i == 0 && blockIdx.x == 0) rp[NT] = E2;
}

__global__ __launch_bounds__(256) void k_fill(const int* __restrict__ ei, const int* __restrict__ rp,
                                              int* __restrict__ fill, int* __restrict__ col) {
    for (int e = blockIdx.x * 256 + threadIdx.x; e < E2; e += gridDim.x * 256) {
        int s = ei[e];
        int d = (e < EG) ? ei[e + EG] : ei[e - EG];
        int slot = rp[d] + atomicAdd(&fill[d], 1);
        col[slot] = s;
    }
}

// ---------------- Weight conversion: fp32 -> bf16, stacked/padded ----------------
__global__ __launch_bounds__(256) void k_wcvt(const float* __restrict__ W1l, const float* __restrict__ W1r,
                                              const float* __restrict__ W2l, const float* __restrict__ W2r,
                                              const float* __restrict__ Wu, const float* __restrict__ Wp,
                                              bf16* __restrict__ B) {
    int i = blockIdx.x * 256 + threadIdx.x;
    if (i < 65536) {
        int layer = i >> 15, rem = i & 32767, o = rem >> 8, k = rem & 255;
        const float* W = layer ? ((k < 128) ? W2l : W2r) : ((k < 128) ? W1l : W1r);
        B[i] = __float2bfloat16(W[o * 128 + (k & 127)]);
    } else if (i < 81920) {
        int rem = i - 65536, o = rem >> 7, k = rem & 127;
        B[i] = __float2bfloat16((k < 100) ? Wu[o * 100 + k] : 0.f);
    } else if (i < 90112) {
        int rem = i - 81920, o = rem >> 6, k = rem & 63;
        B[i] = __float2bfloat16((k < 50) ? Wp[o * 50 + k] : 0.f);
    }
}

// ---------------- MFMA projection: X = relu(in @ Wp^T + b), K zero-padded ----------------
template<int DIN, int KPAD>
__global__ __launch_bounds__(256) void k_projm(const float* __restrict__ in, const bf16* __restrict__ Bp,
                                               const float* __restrict__ bias, bf16* __restrict__ outp,
                                               int nrows, int rowbase) {
    const int lane = threadIdx.x & 63;
    const int wid = threadIdx.x >> 6;
    const int wr = wid >> 1, wc = wid & 1;
    const int r15 = lane & 15, l4 = lane >> 4;
    const int tb = blockIdx.x * 128;
    constexpr int NKS = KPAD / 32;

    f32x4 acc[4][4] = {};
#pragma unroll
    for (int ks = 0; ks < NKS; ks++) {
        int kk = ks * 32 + l4 * 8;
        short8v a[4], b[4];
#pragma unroll
        for (int m = 0; m < 4; m++) {
            int r = tb + wr * 64 + m * 16 + r15;
            if (r > nrows - 1) r = nrows - 1;
            const float* src = in + (size_t)r * DIN + kk;
            short8v v;
            if (ks * 32 + 32 <= DIN) {
                if constexpr (DIN % 4 == 0) {   // 16B-aligned rows -> float4 loads
                    const float4* s4 = (const float4*)src;
                    float4 f0 = s4[0], f1 = s4[1];
                    v[0] = (short)f2bf(f0.x); v[1] = (short)f2bf(f0.y);
                    v[2] = (short)f2bf(f0.z); v[3] = (short)f2bf(f0.w);
                    v[4] = (short)f2bf(f1.x); v[5] = (short)f2bf(f1.y);
                    v[6] = (short)f2bf(f1.z); v[7] = (short)f2bf(f1.w);
                } else {
                    const float2* s2 = (const float2*)src;
                    float2 f0 = s2[0], f1 = s2[1], f2 = s2[2], f3 = s2[3];
                    v[0] = (short)f2bf(f0.x); v[1] = (short)f2bf(f0.y);
                    v[2] = (short)f2bf(f1.x); v[3] = (short)f2bf(f1.y);
                    v[4] = (short)f2bf(f2.x); v[5] = (short)f2bf(f2.y);
                    v[6] = (short)f2bf(f3.x); v[7] = (short)f2bf(f3.y);
                }
            } else {
#pragma unroll
                for (int j = 0; j < 8; j++) {
                    float f = (kk + j < DIN) ? src[j] : 0.f;
                    v[j] = (short)f2bf(f);
                }
            }
            a[m] = v;
        }
#pragma unroll
        for (int n = 0; n < 4; n++) {
            int c = wc * 64 + n * 16 + r15;
            b[n] = *(const short8v*)(Bp + (size_t)c * KPAD + kk);
        }
#pragma unroll
        for (int m = 0; m < 4; m++)
#pragma unroll
            for (int n = 0; n < 4; n++)
                acc[m][n] = __builtin_amdgcn_mfma_f32_16x16x32_bf16(a[m], b[n], acc[m][n], 0, 0, 0);
    }
    float bcol[4];
#pragma unroll
    for (int n = 0; n < 4; n++) bcol[n] = bias[wc * 64 + n * 16 + r15];
#pragma unroll
    for (int m = 0; m < 4; m++)
#pragma unroll
        for (int n = 0; n < 4; n++)
#pragma unroll
            for (int g = 0; g < 4; g++) {
                int row = tb + wr * 64 + m * 16 + l4 * 4 + g;
                if (row < nrows) {
                    float v = fmaxf(acc[m][n][g] + bcol[n], 0.f);
                    outp[(size_t)(rowbase + row) * HD + wc * 64 + n * 16 + r15] = __float2bfloat16(v);
                }
            }
}

// ================= SPLIT PATH =================
// ---------------- SpMM gather: M[n] = mean of f(hin[neighbors]) ----------------
// One node per 16-lane group, 4 groups/wave, no LDS, no barrier — max TLP.
template<bool NORM>
__global__ __launch_bounds__(256) void k_spmm(const bf16* __restrict__ hin, const float* __restrict__ ssv,
                                              const int* __restrict__ rp, const int* __restrict__ col,
                                              bf16* __restrict__ M) {
    const int tid = threadIdx.x;
    const int gid = tid >> 4, l16 = tid & 15;
    const int fo = l16 * 8;
    float sv[8], tv[8];
    if (NORM) {
#pragma unroll
        for (int j = 0; j < 8; j++) { sv[j] = ssv[fo + j]; tv[j] = ssv[HD + fo + j]; }
    }
    for (int n = blockIdx.x * 16 + gid; n < NT; n += gridDim.x * 16) {
        int s0 = rp[n], s1 = rp[n + 1];
        float a[8] = {};
        for (int p = s0; p < s1; p += 4) {
            int i1 = min(p + 1, s1 - 1), i2 = min(p + 2, s1 - 1), i3 = min(p + 3, s1 - 1);
            int c0 = col[p], c1 = col[i1], c2 = col[i2], c3 = col[i3];
            short8v u0 = *(const short8v*)(hin + (size_t)c0 * HD + fo);
            short8v u1 = *(const short8v*)(hin + (size_t)c1 * HD + fo);
            short8v u2 = *(const short8v*)(hin + (size_t)c2 * HD + fo);
            short8v u3 = *(const short8v*)(hin + (size_t)c3 * HD + fo);
            float m1 = (p + 1 < s1) ? 1.f : 0.f;
            float m2 = (p + 2 < s1) ? 1.f : 0.f;
            float m3 = (p + 3 < s1) ? 1.f : 0.f;
#pragma unroll
            for (int j = 0; j < 8; j++) {
                float v0 = b2f(u0[j]), v1 = b2f(u1[j]), v2 = b2f(u2[j]), v3 = b2f(u3[j]);
                if (NORM) {
                    v0 = fmaxf(fmaf(v0, sv[j], tv[j]), 0.f);
                    v1 = fmaxf(fmaf(v1, sv[j], tv[j]), 0.f);
                    v2 = fmaxf(fmaf(v2, sv[j], tv[j]), 0.f);
                    v3 = fmaxf(fmaf(v3, sv[j], tv[j]), 0.f);
                }
                a[j] += v0 + m1 * v1 + m2 * v2 + m3 * v3;
            }
        }
        float inv = 1.f / (float)max(s1 - s0, 1);
        short8v w;
#pragma unroll
        for (int j = 0; j < 8; j++) w[j] = (short)f2bf(a[j] * inv);
        *(short8v*)(M + (size_t)n * HD + fo) = w;
    }
}

// ---------------- Dense GEMM: out = [M | f(hin)] @ B^T + bias (+BN stats) ----------------
// Quadrant waves, direct global A-loads, one barrier (M/out alias safety).
template<bool NORM>
__global__ __launch_bounds__(256) void k_dense(const bf16* __restrict__ Min, const bf16* __restrict__ hin,
                                               const float* __restrict__ ssv,
                                               const bf16* __restrict__ Bmat, const float* __restrict__ blv,
                                               bf16* __restrict__ outp, float* __restrict__ spart,
                                               int store_n) {
    const int lane = threadIdx.x & 63;
    const int wid = threadIdx.x >> 6;
    const int wr = wid >> 1, wc = wid & 1;
    const int r15 = lane & 15, l4 = lane >> 4;
    const int tb = blockIdx.x * 128;

    f32x4 acc[4][4] = {};
#pragma unroll
    for (int ks = 0; ks < 8; ks++) {
        short8v a[4], b[4];
        if (ks < 4) {
            int k0 = ks * 32 + l4 * 8;
#pragma unroll
            for (int m = 0; m < 4; m++) {
                int r = tb + wr * 64 + m * 16 + r15; if (r > NT - 1) r = NT - 1;
                a[m] = *(const short8v*)(Min + (size_t)r * HD + k0);
            }
        } else {
            int k2 = (ks - 4) * 32 + l4 * 8;
            float sv2[8], tv2[8];
            if (NORM) {
#pragma unroll
                for (int j = 0; j < 8; j++) { sv2[j] = ssv[k2 + j]; tv2[j] = ssv[HD + k2 + j]; }
            }
#pragma unroll
            for (int m = 0; m < 4; m++) {
                int r = tb + wr * 64 + m * 16 + r15; if (r > NT - 1) r = NT - 1;
                short8v v = *(const short8v*)(hin + (size_t)r * HD + k2);
                if (NORM) {
#pragma unroll
                    for (int j = 0; j < 8; j++) {
                        float f = b2f(v[j]);
                        f = fmaxf(fmaf(f, sv2[j], tv2[j]), 0.f);
                        v[j] = (short)f2bf(f);
                    }
                }
                a[m] = v;
            }
        }
#pragma unroll
        for (int n = 0; n < 4; n++) {
            int c = wc * 64 + n * 16 + r15;
            b[n] = *(const short8v*)(Bmat + (size_t)c * 256 + ks * 32 + l4 * 8);
        }
#pragma unroll
        for (int m = 0; m < 4; m++)
#pragma unroll
            for (int n = 0; n < 4; n++)
                acc[m][n] = __builtin_amdgcn_mfma_f32_16x16x32_bf16(a[m], b[n], acc[m][n], 0, 0, 0);
    }

    __syncthreads();   // all M reads complete before any aliased store (layer 2)

    float bcol[4];
#pragma unroll
    for (int n = 0; n < 4; n++) bcol[n] = blv[wc * 64 + n * 16 + r15];
    float ls[4] = {0.f, 0.f, 0.f, 0.f}, lq[4] = {0.f, 0.f, 0.f, 0.f};
#pragma unroll
    for (int m = 0; m < 4; m++)
#pragma unroll
        for (int n = 0; n < 4; n++)
#pragma unroll
            for (int gg = 0; gg < 4; gg++) {
                int row = tb + wr * 64 + m * 16 + l4 * 4 + gg;
                float v = acc[m][n][gg] + bcol[n];
                if (row < NT) { ls[n] += v; lq[n] += v * v; }
                if (row < store_n)
                    outp[(size_t)row * HD + wc * 64 + n * 16 + r15] = __float2bfloat16(v);
            }
    int part = (blockIdx.x & 31) * 256;
#pragma unroll
    for (int n = 0; n < 4; n++) {
        float s = ls[n], q2 = lq[n];
        s  += __shfl_xor(s, 16);  s  += __shfl_xor(s, 32);
        q2 += __shfl_xor(q2, 16); q2 += __shfl_xor(q2, 32);
        if (l4 == 0) {
            int c = wc * 64 + n * 16 + r15;
            atomicAdd(&spart[part + c], s);
            atomicAdd(&spart[part + 128 + c], q2);
        }
    }
}

// ================= FUSED FALLBACK (round-5, verified 452us) =================
template<bool NORM>
__global__ __launch_bounds__(256) void k_gemm(const bf16* __restrict__ hin, const float* __restrict__ ssv,
                                              const int* __restrict__ rp, const int* __restrict__ col,
                                              const bf16* __restrict__ Bmat, const float* __restrict__ blv,
                                              bf16* __restrict__ outp, float* __restrict__ spart,
                                              int store_n) {
    int g = blockIdx.x / 5, pos = blockIdx.x % 5;
    int tile = (pos < 4) ? (g * 4 + pos) : (1563 + g);
    if (pos < 4 && tile > 1562) return;

    __shared__ unsigned int mrow[8192];
    const int tid = threadIdx.x;
    const int lane = tid & 63;
    const int wid = tid >> 6;
    const int g16 = lane >> 4, l16 = lane & 15;
    const int tb = tile * 128;
    const int wnb = wid * 32;
    const int fo = l16 * 8;

    float sv[8], tv[8];
    if (NORM) {
#pragma unroll
        for (int j = 0; j < 8; j++) { sv[j] = ssv[fo + j]; tv[j] = ssv[HD + fo + j]; }
    }
    int rpv = 0;
    if (lane <= 32) rpv = rp[min(tb + wnb + lane, NT)];

    for (int t = 0; t < 4; t++) {
        int nlA = wnb + t * 8 + g16;
        int nlB = nlA + 4;
        int a0 = __shfl(rpv, t * 8 + g16),     a1 = __shfl(rpv, t * 8 + g16 + 1);
        int b0 = __shfl(rpv, t * 8 + g16 + 4), b1 = __shfl(rpv, t * 8 + g16 + 5);
        if (tb + nlA >= NT) { a0 = 0; a1 = 0; }
        if (tb + nlB >= NT) { b0 = 0; b1 = 0; }
        float accA[8] = {}, accB[8] = {};
        int pA = a0, pB = b0;
        while (pA < a1 || pB < b1) {
            int iA0 = (pA     < a1) ? pA     : 0;
            int iA1 = (pA + 1 < a1) ? pA + 1 : 0;
            int iA2 = (pA + 2 < a1) ? pA + 2 : 0;
            int iA3 = (pA + 3 < a1) ? pA + 3 : 0;
            int iB0 = (pB     < b1) ? pB     : 0;
            int iB1 = (pB + 1 < b1) ? pB + 1 : 0;
            int iB2 = (pB + 2 < b1) ? pB + 2 : 0;
            int iB3 = (pB + 3 < b1) ? pB + 3 : 0;
            int cA0 = col[iA0], cA1 = col[iA1], cA2 = col[iA2], cA3 = col[iA3];
            int cB0 = col[iB0], cB1 = col[iB1], cB2 = col[iB2], cB3 = col[iB3];
            short8v uA0 = *(const short8v*)(hin + (size_t)cA0 * HD + fo);
            short8v uA1 = *(const short8v*)(hin + (size_t)cA1 * HD + fo);
            short8v uA2 = *(const short8v*)(hin + (size_t)cA2 * HD + fo);
            short8v uA3 = *(const short8v*)(hin + (size_t)cA3 * HD + fo);
            short8v uB0 = *(const short8v*)(hin + (size_t)cB0 * HD + fo);
            short8v uB1 = *(const short8v*)(hin + (size_t)cB1 * HD + fo);
            short8v uB2 = *(const short8v*)(hin + (size_t)cB2 * HD + fo);
            short8v uB3 = *(const short8v*)(hin + (size_t)cB3 * HD + fo);
            float mA0 = (pA     < a1) ? 1.f : 0.f;
            float mA1 = (pA + 1 < a1) ? 1.f : 0.f;
            float mA2 = (pA + 2 < a1) ? 1.f : 0.f;
            float mA3 = (pA + 3 < a1) ? 1.f : 0.f;
            float mB0 = (pB     < b1) ? 1.f : 0.f;
            float mB1 = (pB + 1 < b1) ? 1.f : 0.f;
            float mB2 = (pB + 2 < b1) ? 1.f : 0.f;
            float mB3 = (pB + 3 < b1) ? 1.f : 0.f;
#pragma unroll
            for (int j = 0; j < 8; j++) {
                float vA0 = b2f(uA0[j]), vA1 = b2f(uA1[j]), vA2 = b2f(uA2[j]), vA3 = b2f(uA3[j]);
                float vB0 = b2f(uB0[j]), vB1 = b2f(uB1[j]), vB2 = b2f(uB2[j]), vB3 = b2f(uB3[j]);
                if (NORM) {
                    vA0 = fmaxf(fmaf(vA0, sv[j], tv[j]), 0.f);
                    vA1 = fmaxf(fmaf(vA1, sv[j], tv[j]), 0.f);
                    vA2 = fmaxf(fmaf(vA2, sv[j], tv[j]), 0.f);
                    vA3 = fmaxf(fmaf(vA3, sv[j], tv[j]), 0.f);
                    vB0 = fmaxf(fmaf(vB0, sv[j], tv[j]), 0.f);
                    vB1 = fmaxf(fmaf(vB1, sv[j], tv[j]), 0.f);
                    vB2 = fmaxf(fmaf(vB2, sv[j], tv[j]), 0.f);
                    vB3 = fmaxf(fmaf(vB3, sv[j], tv[j]), 0.f);
                }
                accA[j] += mA0 * vA0 + mA1 * vA1 + mA2 * vA2 + mA3 * vA3;
                accB[j] += mB0 * vB0 + mB1 * vB1 + mB2 * vB2 + mB3 * vB3;
            }
            pA += 4; pB += 4;
        }
        float invA = 1.f / (float)max(a1 - a0, 1);
        float invB = 1.f / (float)max(b1 - b0, 1);
        short8v wA, wB;
#pragma unroll
        for (int j = 0; j < 8; j++) {
            wA[j] = (short)f2bf(accA[j] * invA);
            wB[j] = (short)f2bf(accB[j] * invB);
        }
        int byteA = (nlA * 256 + l16 * 16) ^ ((nlA & 7) << 4);
        int byteB = (nlB * 256 + l16 * 16) ^ ((nlB & 7) << 4);
        *(short8v*)((char*)mrow + byteA) = wA;
        *(short8v*)((char*)mrow + byteB) = wB;
    }
    __syncthreads();

    const int wr = wid >> 1, wc = wid & 1;
    const int r15 = lane & 15, l4 = lane >> 4;
    f32x4 acc[4][4] = {};
#pragma unroll
    for (int ks = 0; ks < 8; ks++) {
        short8v a[4], b[4];
        if (ks < 4) {
            int kb = ks * 64 + l4 * 16;
#pragma unroll
            for (int m = 0; m < 4; m++) {
                int r = wr * 64 + m * 16 + r15;
                int byte = (r * 256 + kb) ^ ((r & 7) << 4);
                a[m] = *(const short8v*)((const char*)mrow + byte);
            }
        } else {
            int k2 = (ks - 4) * 32 + l4 * 8;
            float sv2[8], tv2[8];
            if (NORM) {
#pragma unroll
                for (int j = 0; j < 8; j++) { sv2[j] = ssv[k2 + j]; tv2[j] = ssv[HD + k2 + j]; }
            }
#pragma unroll
            for (int m = 0; m < 4; m++) {
                int r = tb + wr * 64 + m * 16 + r15; if (r > NT - 1) r = NT - 1;
                short8v v = *(const short8v*)(hin + (size_t)r * HD + k2);
                if (NORM) {
#pragma unroll
                    for (int j = 0; j < 8; j++) {
                        float f = b2f(v[j]);
                        f = fmaxf(fmaf(f, sv2[j], tv2[j]), 0.f);
                        v[j] = (short)f2bf(f);
                    }
                }
                a[m] = v;
            }
        }
#pragma unroll
        for (int n = 0; n < 4; n++) {
            int c = wc * 64 + n * 16 + r15;
            b[n] = *(const short8v*)(Bmat + (size_t)c * 256 + ks * 32 + l4 * 8);
        }
#pragma unroll
        for (int m = 0; m < 4; m++)
#pragma unroll
            for (int n = 0; n < 4; n++)
                acc[m][n] = __builtin_amdgcn_mfma_f32_16x16x32_bf16(a[m], b[n], acc[m][n], 0, 0, 0);
    }

    float bcol[4];
#pragma unroll
    for (int n = 0; n < 4; n++) bcol[n] = blv[wc * 64 + n * 16 + r15];
    float ls[4] = {0.f, 0.f, 0.f, 0.f}, lq[4] = {0.f, 0.f, 0.f, 0.f};
#pragma unroll
    for (int m = 0; m < 4; m++)
#pragma unroll
        for (int n = 0; n < 4; n++)
#pragma unroll
            for (int gg = 0; gg < 4; gg++) {
                int row = tb + wr * 64 + m * 16 + l4 * 4 + gg;
                float v = acc[m][n][gg] + bcol[n];
                if (row < NT) { ls[n] += v; lq[n] += v * v; }
                if (row < store_n)
                    outp[(size_t)row * HD + wc * 64 + n * 16 + r15] = __float2bfloat16(v);
            }
    int part = (tile & 31) * 256;
#pragma unroll
    for (int n = 0; n < 4; n++) {
        float s = ls[n], q2 = lq[n];
        s  += __shfl_xor(s, 16);  s  += __shfl_xor(s, 32);
        q2 += __shfl_xor(q2, 16); q2 += __shfl_xor(q2, 32);
        if (l4 == 0) {
            int c = wc * 64 + n * 16 + r15;
            atomicAdd(&spart[part + c], s);
            atomicAdd(&spart[part + 128 + c], q2);
        }
    }
}

// ---------------- BN finalize ----------------
__global__ void k_fin(const float* __restrict__ sp, const float* __restrict__ g,
                      const float* __restrict__ be, float* __restrict__ ssout) {
    int j = threadIdx.x;   // 128
    float m = 0.f, q = 0.f;
    for (int i = 0; i < 32; i++) { m += sp[i * 256 + j]; q += sp[i * 256 + 128 + j]; }
    m *= (1.f / (float)NT);
    q = q * (1.f / (float)NT) - m * m;
    float s = g[j] * rsqrtf(q + 1e-5f);
    ssout[j] = s;
    ssout[HD + j] = be[j] - m * s;
}

// ---------------- Final: out = (relu(bn(raw2)) + x)[:NU] @ Wout^T + bout ----------------
// 4 rows per wave, 16B loads, 16-lane reduce.
__global__ __launch_bounds__(256) void k_out(const bf16* __restrict__ r2, const float* __restrict__ ss,
                                             const bf16* __restrict__ x, const float* __restrict__ wout,
                                             const float* __restrict__ bout, float* __restrict__ outp) {
    int lane = threadIdx.x & 63;
    int wv = (blockIdx.x * blockDim.x + threadIdx.x) >> 6;
    int nwv = (gridDim.x * blockDim.x) >> 6;
    int g16 = lane >> 4, l16 = lane & 15;
    int fo = l16 * 8;
    float s8[8], t8[8], w8[8];
#pragma unroll
    for (int j = 0; j < 8; j++) {
        s8[j] = ss[fo + j]; t8[j] = ss[HD + fo + j]; w8[j] = wout[fo + j];
    }
    float bo = bout[0];
    for (int r0 = wv * 4; r0 < NUU; r0 += nwv * 4) {
        int row = r0 + g16;           // NUU % 4 == 0, always valid
        short8v a  = *(const short8v*)(r2 + (size_t)row * HD + fo);
        short8v xx = *(const short8v*)(x  + (size_t)row * HD + fo);
        float acc = 0.f;
#pragma unroll
        for (int j = 0; j < 8; j++) {
            float h = fmaxf(fmaf(b2f(a[j]), s8[j], t8[j]), 0.f) + b2f(xx[j]);
            acc += h * w8[j];
        }
        acc += __shfl_xor(acc, 1);
        acc += __shfl_xor(acc, 2);
        acc += __shfl_xor(acc, 4);
        acc += __shfl_xor(acc, 8);
        if (l16 == 0) outp[row] = acc + bo;
    }
}

extern "C" void kernel_launch(void* const* d_in, const int* in_sizes, int n_in,
                              void* d_out, int out_size, void* d_ws, size_t ws_size,
                              hipStream_t stream) {
    const float* x_u = (const float*)d_in[0];
    const float* x_p = (const float*)d_in[1];
    const int*   ei  = (const int*)d_in[2];
    const float* W_u = (const float*)d_in[3];
    const float* b_u = (const float*)d_in[4];
    const float* W_p = (const float*)d_in[5];
    const float* b_p = (const float*)d_in[6];
    const float* W1l = (const float*)d_in[7];
    const float* b1l = (const float*)d_in[8];
    const float* W1r = (const float*)d_in[9];
    const float* g1  = (const float*)d_in[10];
    const float* be1 = (const float*)d_in[11];
    const float* W2l = (const float*)d_in[12];
    const float* b2l = (const float*)d_in[13];
    const float* W2r = (const float*)d_in[14];
    const float* g2  = (const float*)d_in[15];
    const float* be2 = (const float*)d_in[16];
    const float* Wout = (const float*)d_in[17];
    const float* bout = (const float*)d_in[18];
    float* out = (float*)d_out;
    char* ws = (char*)d_ws;

    if (ws_size >= WS_SPLIT) {
        // ---------- SPLIT PATH ----------
        int*  cnt    = (int*)(ws + CNT2_OFF);
        float* spart = (float*)(ws + SPART2_OFF);
        float* ssbuf = (float*)(ws + SS2_OFF);
        int*  rp     = (int*)(ws + RPTR2_OFF);
        int*  bsum   = (int*)(ws + BSUM2_OFF);
        bf16* Bmat   = (bf16*)(ws + BMAT2_OFF);
        int*  col    = (int*)(ws + COL2_OFF);
        bf16* X      = (bf16*)(ws + X2_OFF);
        bf16* R1     = (bf16*)(ws + R1B_OFF);
        bf16* MC     = (bf16*)(ws + C2_OFF);   // M1, M2 and R2 share this region

        k_zero<<<1043, 256, 0, stream>>>(cnt, 266896);   // cnt + spart + ss contiguous
        k_wcvt<<<352, 256, 0, stream>>>(W1l, W1r, W2l, W2r, W_u, W_p, Bmat);

        k_count<<<1024, 256, 0, stream>>>(ei, cnt);
        k_scan1<<<NBLK_SCAN, 256, 0, stream>>>(cnt, bsum);
        k_scan2<<<1, 1024, 0, stream>>>(bsum);
        k_scan3<<<NBLK_SCAN, 256, 0, stream>>>(cnt, bsum, rp);
        k_zero<<<977, 256, 0, stream>>>(cnt, NT);
        k_fill<<<1024, 256, 0, stream>>>(ei, rp, cnt, col);

        k_projm<100, 128><<<1563, 256, 0, stream>>>(x_u, Bmat + 65536, b_u, X, NUU, 0);
        k_projm<50, 64><<<391, 256, 0, stream>>>(x_p, Bmat + 81920, b_p, X, NPP, NUU);

        // Layer 1
        k_spmm<false><<<2048, 256, 0, stream>>>(X, nullptr, rp, col, MC);
        k_dense<false><<<1954, 256, 0, stream>>>(MC, X, nullptr, Bmat, b1l, R1, spart, NT);
        k_fin<<<1, 128, 0, stream>>>(spart, g1, be1, ssbuf);

        // Layer 2 (R2 aliases M2; per-block read-before-write + barrier makes it safe)
        k_spmm<true><<<2048, 256, 0, stream>>>(R1, ssbuf, rp, col, MC);
        k_dense<true><<<1954, 256, 0, stream>>>(MC, R1, ssbuf, Bmat + 32768, b2l, MC, spart + 8192, NUU);
        k_fin<<<1, 128, 0, stream>>>(spart + 8192, g2, be2, ssbuf + 256);

        k_out<<<1024, 256, 0, stream>>>(MC, ssbuf + 256, X, Wout, bout, out);
        return;
    }

    // ---------- FUSED FALLBACK (round-5 structure) ----------
    if (ws_size < WS_NEED) {
        k_zero<<<512, 256, 0, stream>>>((int*)d_out, out_size);
        return;
    }
    bf16* X      = (bf16*)(ws + X_OFF);
    bf16* R1     = (bf16*)(ws + R1_OFF);
    bf16* R2     = (bf16*)(ws + R2_OFF);
    int*  cnt    = (int*)(ws + CNT_OFF);
    float* spart = (float*)(ws + SPART_OFF);
    float* ssbuf = (float*)(ws + SS_OFF);
    int*  rp     = (int*)(ws + RPTR_OFF);
    int*  bsum   = (int*)(ws + BSUM_OFF);
    bf16* Bmat   = (bf16*)(ws + BMAT_OFF);
    int*  col    = (int*)(ws + COL_OFF);

    k_zero<<<1043, 256, 0, stream>>>(cnt, 266896);
    k_wcvt<<<352, 256, 0, stream>>>(W1l, W1r, W2l, W2r, W_u, W_p, Bmat);

    k_count<<<1024, 256, 0, stream>>>(ei, cnt);
    k_scan1<<<NBLK_SCAN, 256, 0, stream>>>(cnt, bsum);
    k_scan2<<<1, 1024, 0, stream>>>(bsum);
    k_scan3<<<NBLK_SCAN, 256, 0, stream>>>(cnt, bsum, rp);
    k_zero<<<977, 256, 0, stream>>>(cnt, NT);
    k_fill<<<1024, 256, 0, stream>>>(ei, rp, cnt, col);

    k_projm<100, 128><<<1563, 256, 0, stream>>>(x_u, Bmat + 65536, b_u, X, NUU, 0);
    k_projm<50, 64><<<391, 256, 0, stream>>>(x_p, Bmat + 81920, b_p, X, NPP, NUU);

    k_gemm<false><<<1955, 256, 0, stream>>>(X, nullptr, rp, col, Bmat, b1l, R1, spart, NT);
    k_fin<<<1, 128, 0, stream>>>(spart, g1, be1, ssbuf);

    k_gemm<true><<<1955, 256, 0, stream>>>(R1, ssbuf, rp, col, Bmat + 32768, b2l, R2, spart + 8192, NUU);
    k_fin<<<1, 128, 0, stream>>>(spart + 8192, g2, be2, ssbuf + 256);

    k_out<<<1024, 256, 0, stream>>>(R2, ssbuf + 256, X, Wout, bout, out);
}